// Round 1
// baseline (6884.909 us; speedup 1.0000x reference)
//
#include <hip/hip_runtime.h>
#include <math.h>

#define NT 64
#define NB 1024
#define NC 512
#define HH 512
#define EE 128
#define NCLS 97
#define STEPS 32

#define BM 64
#define BN 64
#define BK 16

// C[M,N] = A[M,K] @ B[N,K]^T (+ bias[N]); M%64==0, N%64==0, K%16==0
__global__ __launch_bounds__(256) void gemm_bt_f32(
    const float* __restrict__ A, const float* __restrict__ B,
    const float* __restrict__ bias, float* __restrict__ C,
    int M, int N, int K) {
  __shared__ float As[BK][BM + 4];
  __shared__ float Bs[BK][BN + 4];
  const int bm = blockIdx.y * BM;
  const int bn = blockIdx.x * BN;
  const int tid = threadIdx.x;
  const int tx = tid & 15, ty = tid >> 4;
  const int lr = tid >> 2;           // 0..63 tile row
  const int lc = (tid & 3) << 2;     // 0,4,8,12 k-offset
  float acc[4][4] = {{0.f, 0.f, 0.f, 0.f}, {0.f, 0.f, 0.f, 0.f},
                     {0.f, 0.f, 0.f, 0.f}, {0.f, 0.f, 0.f, 0.f}};
  const float* Ap = A + (size_t)(bm + lr) * K + lc;
  const float* Bp = B + (size_t)(bn + lr) * K + lc;
  for (int k0 = 0; k0 < K; k0 += BK) {
    float4 av = *(const float4*)(Ap + k0);
    float4 bv = *(const float4*)(Bp + k0);
    As[lc + 0][lr] = av.x; As[lc + 1][lr] = av.y;
    As[lc + 2][lr] = av.z; As[lc + 3][lr] = av.w;
    Bs[lc + 0][lr] = bv.x; Bs[lc + 1][lr] = bv.y;
    Bs[lc + 2][lr] = bv.z; Bs[lc + 3][lr] = bv.w;
    __syncthreads();
#pragma unroll
    for (int kk = 0; kk < BK; ++kk) {
      float a0[4], b0[4];
      *(float4*)a0 = *(const float4*)&As[kk][ty << 2];
      *(float4*)b0 = *(const float4*)&Bs[kk][tx << 2];
#pragma unroll
      for (int i = 0; i < 4; ++i)
#pragma unroll
        for (int j = 0; j < 4; ++j) acc[i][j] += a0[i] * b0[j];
    }
    __syncthreads();
  }
  float bcol[4] = {0.f, 0.f, 0.f, 0.f};
  if (bias) *(float4*)bcol = *(const float4*)(bias + bn + (tx << 2));
#pragma unroll
  for (int i = 0; i < 4; ++i) {
    int row = bm + (ty << 2) + i;
    float4 o;
    o.x = acc[i][0] + bcol[0];
    o.y = acc[i][1] + bcol[1];
    o.z = acc[i][2] + bcol[2];
    o.w = acc[i][3] + bcol[3];
    *(float4*)(C + (size_t)row * N + bn + (tx << 2)) = o;
  }
}

// e[b][t] = sum_h tanh(fp[t*NB+b][h] + hproj[b][h]) * w_score[h]
__global__ __launch_bounds__(256) void e_kernel(
    const float* __restrict__ fp, const float* __restrict__ hproj,
    const float* __restrict__ w_score, float* __restrict__ e) {
  int wave = threadIdx.x >> 6;
  int lane = threadIdx.x & 63;
  int m = blockIdx.x * 4 + wave;  // < NT*NB
  int b = m & (NB - 1);
  const float* fr = fp + (size_t)m * HH;
  const float* hr = hproj + (size_t)b * HH;
  float acc = 0.f;
  int h0 = lane * 8;
#pragma unroll
  for (int i = 0; i < 2; ++i) {
    float4 f = *(const float4*)(fr + h0 + i * 4);
    float4 hp = *(const float4*)(hr + h0 + i * 4);
    float4 w = *(const float4*)(w_score + h0 + i * 4);
    acc += tanhf(f.x + hp.x) * w.x;
    acc += tanhf(f.y + hp.y) * w.y;
    acc += tanhf(f.z + hp.z) * w.z;
    acc += tanhf(f.w + hp.w) * w.w;
  }
#pragma unroll
  for (int off = 32; off > 0; off >>= 1) acc += __shfl_down(acc, off, 64);
  if (lane == 0) {
    int t = m >> 10;
    e[b * NT + t] = acc;
  }
}

// per b: alpha = softmax_t(e[b][:]); x[b][:NC] = sum_t alpha[t]*feats[t][b][:];
// x[b][NC:] = char_emb[tgt[b]]
__global__ __launch_bounds__(256) void ctx_kernel(
    const float* __restrict__ e, const float* __restrict__ feats,
    const int* __restrict__ tgt, const float* __restrict__ char_emb,
    float* __restrict__ x) {
  __shared__ float alpha[NT];
  int b = blockIdx.x;
  int tid = threadIdx.x;
  if (tid < 64) {
    float v = e[b * NT + tid];
    float mx = v;
#pragma unroll
    for (int off = 32; off > 0; off >>= 1) mx = fmaxf(mx, __shfl_xor(mx, off, 64));
    float p = expf(v - mx);
    float sum = p;
#pragma unroll
    for (int off = 32; off > 0; off >>= 1) sum += __shfl_xor(sum, off, 64);
    alpha[tid] = p / sum;
  }
  __syncthreads();
#pragma unroll
  for (int cc = 0; cc < 2; ++cc) {
    int c = tid + cc * 256;
    float acc = 0.f;
    for (int t = 0; t < NT; ++t)
      acc += alpha[t] * feats[((size_t)t * NB + b) * NC + c];
    x[(size_t)b * (NC + EE) + c] = acc;
  }
  if (tid < EE) {
    int tg = tgt[b];
    x[(size_t)b * (NC + EE) + NC + tid] = char_emb[tg * EE + tid];
  }
}

__global__ __launch_bounds__(256) void gate_kernel(
    const float* __restrict__ gi, const float* __restrict__ gh,
    const float* __restrict__ hcur, float* __restrict__ hnew) {
  int idx = blockIdx.x * 256 + threadIdx.x;  // < NB*HH
  int b = idx >> 9, j = idx & (HH - 1);
  const float* gib = gi + (size_t)b * (3 * HH);
  const float* ghb = gh + (size_t)b * (3 * HH);
  float ir = gib[j], iz = gib[HH + j], in = gib[2 * HH + j];
  float hr = ghb[j], hz = ghb[HH + j], hn = ghb[2 * HH + j];
  float r = 1.f / (1.f + expf(-(ir + hr)));
  float z = 1.f / (1.f + expf(-(iz + hz)));
  float n = tanhf(in + r * hn);
  float h = hcur[idx];
  hnew[idx] = (1.f - z) * n + z * h;
}

// logits = hnew @ w_gen^T + b_gen; write valid rows; tgt = argmax+1
__global__ __launch_bounds__(128) void logits_kernel(
    const float* __restrict__ hnew, const float* __restrict__ w_gen,
    const float* __restrict__ b_gen, const int* __restrict__ tl,
    const int* __restrict__ offs, float* __restrict__ out,
    int* __restrict__ tgt, int step) {
  __shared__ float hs[HH];
  __shared__ float lv[128];
  __shared__ int li[128];
  int b = blockIdx.x;
  int tid = threadIdx.x;
#pragma unroll
  for (int i = 0; i < 4; ++i)
    hs[tid + i * 128] = hnew[(size_t)b * HH + tid + i * 128];
  __syncthreads();
  float acc = -INFINITY;
  if (tid < NCLS) {
    const float4* wr4 = (const float4*)(w_gen + (size_t)tid * HH);
    float s = 0.f;
    for (int k = 0; k < HH / 4; ++k) {
      float4 w = wr4[k];
      s += hs[4 * k + 0] * w.x + hs[4 * k + 1] * w.y +
           hs[4 * k + 2] * w.z + hs[4 * k + 3] * w.w;
    }
    acc = s + b_gen[tid];
    if (step < tl[b]) out[(size_t)(offs[b] + step) * NCLS + tid] = acc;
  }
  lv[tid] = acc;
  li[tid] = tid;
  __syncthreads();
  for (int d = 64; d > 0; d >>= 1) {
    if (tid < d) {
      float v2 = lv[tid + d];
      int i2 = li[tid + d];
      if (v2 > lv[tid] || (v2 == lv[tid] && i2 < li[tid])) {
        lv[tid] = v2;
        li[tid] = i2;
      }
    }
    __syncthreads();
  }
  if (tid == 0) tgt[b] = li[0] + 1;
}

__global__ __launch_bounds__(1024) void scan_tl(const int* __restrict__ tl,
                                                int* __restrict__ offs) {
  __shared__ int s[NB];
  int t = threadIdx.x;
  s[t] = tl[t];
  __syncthreads();
  for (int d = 1; d < NB; d <<= 1) {
    int v = (t >= d) ? s[t - d] : 0;
    __syncthreads();
    s[t] += v;
    __syncthreads();
  }
  offs[t] = s[t] - tl[t];  // exclusive prefix sum
}

__global__ __launch_bounds__(256) void init_kernel(float* __restrict__ h0,
                                                   int* __restrict__ tgt) {
  int idx = blockIdx.x * 256 + threadIdx.x;
  if (idx < NB * HH) h0[idx] = 0.f;
  if (idx < NB) tgt[idx] = 0;
}

extern "C" void kernel_launch(void* const* d_in, const int* in_sizes, int n_in,
                              void* d_out, int out_size, void* d_ws,
                              size_t ws_size, hipStream_t stream) {
  const float* feats = (const float*)d_in[0];
  const float* w_i2h = (const float*)d_in[1];
  const float* w_h2h = (const float*)d_in[2];
  const float* b_h2h = (const float*)d_in[3];
  const float* w_score = (const float*)d_in[4];
  const float* w_ih = (const float*)d_in[5];
  const float* w_hh = (const float*)d_in[6];
  const float* b_ih = (const float*)d_in[7];
  const float* b_hh = (const float*)d_in[8];
  const float* char_emb = (const float*)d_in[9];
  const float* w_gen = (const float*)d_in[10];
  const float* b_gen = (const float*)d_in[11];
  const int* tl = (const int*)d_in[12];
  float* out = (float*)d_out;

  char* ws = (char*)d_ws;
  float* fp = (float*)ws;    ws += (size_t)NT * NB * HH * 4;   // 134 MB
  float* e = (float*)ws;     ws += (size_t)NB * NT * 4;
  float* x = (float*)ws;     ws += (size_t)NB * (NC + EE) * 4;
  float* gi = (float*)ws;    ws += (size_t)NB * 3 * HH * 4;
  float* gh = (float*)ws;    ws += (size_t)NB * 3 * HH * 4;
  float* h0 = (float*)ws;    ws += (size_t)NB * HH * 4;
  float* h1 = (float*)ws;    ws += (size_t)NB * HH * 4;
  float* hproj = (float*)ws; ws += (size_t)NB * HH * 4;
  int* tgt = (int*)ws;       ws += 4096;
  int* offs = (int*)ws;      ws += 4096;

  hipLaunchKernelGGL(scan_tl, dim3(1), dim3(1024), 0, stream, tl, offs);
  hipLaunchKernelGGL(init_kernel, dim3((NB * HH) / 256), dim3(256), 0, stream,
                     h0, tgt);
  // feats_proj = feats @ w_i2h^T   [65536, 512]
  hipLaunchKernelGGL(gemm_bt_f32, dim3(HH / BN, (NT * NB) / BM), dim3(256), 0,
                     stream, feats, w_i2h, (const float*)nullptr, fp,
                     NT * NB, HH, NC);

  float* hbuf[2] = {h0, h1};
  for (int s = 0; s < STEPS; ++s) {
    float* hc = hbuf[s & 1];
    float* hn = hbuf[(s + 1) & 1];
    // hproj = hc @ w_h2h^T + b_h2h   [1024, 512]
    hipLaunchKernelGGL(gemm_bt_f32, dim3(HH / BN, NB / BM), dim3(256), 0,
                       stream, hc, w_h2h, b_h2h, hproj, NB, HH, HH);
    hipLaunchKernelGGL(e_kernel, dim3(NT * NB / 4), dim3(256), 0, stream, fp,
                       hproj, w_score, e);
    hipLaunchKernelGGL(ctx_kernel, dim3(NB), dim3(256), 0, stream, e, feats,
                       tgt, char_emb, x);
    // gi = x @ w_ih^T + b_ih   [1024, 1536]
    hipLaunchKernelGGL(gemm_bt_f32, dim3(3 * HH / BN, NB / BM), dim3(256), 0,
                       stream, x, w_ih, b_ih, gi, NB, 3 * HH, NC + EE);
    // gh = hc @ w_hh^T + b_hh   [1024, 1536]
    hipLaunchKernelGGL(gemm_bt_f32, dim3(3 * HH / BN, NB / BM), dim3(256), 0,
                       stream, hc, w_hh, b_hh, gh, NB, 3 * HH, HH);
    hipLaunchKernelGGL(gate_kernel, dim3(NB * HH / 256), dim3(256), 0, stream,
                       gi, gh, hc, hn);
    hipLaunchKernelGGL(logits_kernel, dim3(NB), dim3(128), 0, stream, hn,
                       w_gen, b_gen, tl, offs, out, tgt, s);
  }
}

// Round 2
// 5340.489 us; speedup vs baseline: 1.2892x; 1.2892x over previous
//
#include <hip/hip_runtime.h>
#include <math.h>

#define NT 64
#define NB 1024
#define NC 512
#define HH 512
#define EE 128
#define NCLS 97
#define STEPS 32

// ---------------- big GEMM: C[M,N] = A[M,K] @ B[N,K]^T, 128x128 tile, 8x8 micro
__global__ __launch_bounds__(256) void gemm_bt_128(
    const float* __restrict__ A, const float* __restrict__ B,
    float* __restrict__ C, int M, int N, int K) {
  __shared__ float As[16][132];
  __shared__ float Bs[16][132];
  const int bm = blockIdx.y * 128;
  const int bn = blockIdx.x * 128;
  const int tid = threadIdx.x;
  const int tx = tid & 15, ty = tid >> 4;
  const int sr = tid >> 1;         // 0..127
  const int sk = (tid & 1) * 8;    // 0 or 8
  float acc[8][8];
#pragma unroll
  for (int i = 0; i < 8; ++i)
#pragma unroll
    for (int j = 0; j < 8; ++j) acc[i][j] = 0.f;
  const float* Ap = A + (size_t)(bm + sr) * K + sk;
  const float* Bp = B + (size_t)(bn + sr) * K + sk;
  for (int k0 = 0; k0 < K; k0 += 16) {
    float4 a0 = *(const float4*)(Ap + k0);
    float4 a1 = *(const float4*)(Ap + k0 + 4);
    float4 b0 = *(const float4*)(Bp + k0);
    float4 b1 = *(const float4*)(Bp + k0 + 4);
    As[sk + 0][sr] = a0.x; As[sk + 1][sr] = a0.y;
    As[sk + 2][sr] = a0.z; As[sk + 3][sr] = a0.w;
    As[sk + 4][sr] = a1.x; As[sk + 5][sr] = a1.y;
    As[sk + 6][sr] = a1.z; As[sk + 7][sr] = a1.w;
    Bs[sk + 0][sr] = b0.x; Bs[sk + 1][sr] = b0.y;
    Bs[sk + 2][sr] = b0.z; Bs[sk + 3][sr] = b0.w;
    Bs[sk + 4][sr] = b1.x; Bs[sk + 5][sr] = b1.y;
    Bs[sk + 6][sr] = b1.z; Bs[sk + 7][sr] = b1.w;
    __syncthreads();
#pragma unroll
    for (int kk = 0; kk < 16; ++kk) {
      float a[8], b[8];
      *(float4*)&a[0] = *(const float4*)&As[kk][ty * 8];
      *(float4*)&a[4] = *(const float4*)&As[kk][ty * 8 + 4];
      *(float4*)&b[0] = *(const float4*)&Bs[kk][tx * 8];
      *(float4*)&b[4] = *(const float4*)&Bs[kk][tx * 8 + 4];
#pragma unroll
      for (int i = 0; i < 8; ++i)
#pragma unroll
        for (int j = 0; j < 8; ++j) acc[i][j] += a[i] * b[j];
    }
    __syncthreads();
  }
#pragma unroll
  for (int i = 0; i < 8; ++i) {
    int row = bm + ty * 8 + i;
    float4 o0, o1;
    o0.x = acc[i][0]; o0.y = acc[i][1]; o0.z = acc[i][2]; o0.w = acc[i][3];
    o1.x = acc[i][4]; o1.y = acc[i][5]; o1.z = acc[i][6]; o1.w = acc[i][7];
    *(float4*)(C + (size_t)row * N + bn + tx * 8) = o0;
    *(float4*)(C + (size_t)row * N + bn + tx * 8 + 4) = o1;
  }
}

// ---------------- step GEMM: C[.,bn:bn+64] += A @ B^T (+bias), 64x64 tile, BK=32
__global__ __launch_bounds__(256) void gemm_bt_64(
    const float* __restrict__ A, int lda, const float* __restrict__ B, int ldb,
    const float* __restrict__ bias, float* __restrict__ C, int ldc, int K) {
  __shared__ float As[32][68];
  __shared__ float Bs[32][68];
  const int bm = blockIdx.y * 64;
  const int bn = blockIdx.x * 64;
  const int tid = threadIdx.x;
  const int tx = tid & 15, ty = tid >> 4;
  const int sr = tid >> 2;         // 0..63
  const int sk = (tid & 3) * 8;    // 0,8,16,24
  float acc[4][4] = {{0.f, 0.f, 0.f, 0.f}, {0.f, 0.f, 0.f, 0.f},
                     {0.f, 0.f, 0.f, 0.f}, {0.f, 0.f, 0.f, 0.f}};
  const float* Ap = A + (size_t)(bm + sr) * lda + sk;
  const float* Bp = B + (size_t)(bn + sr) * ldb + sk;
  for (int k0 = 0; k0 < K; k0 += 32) {
    float4 a0 = *(const float4*)(Ap + k0);
    float4 a1 = *(const float4*)(Ap + k0 + 4);
    float4 b0 = *(const float4*)(Bp + k0);
    float4 b1 = *(const float4*)(Bp + k0 + 4);
    As[sk + 0][sr] = a0.x; As[sk + 1][sr] = a0.y;
    As[sk + 2][sr] = a0.z; As[sk + 3][sr] = a0.w;
    As[sk + 4][sr] = a1.x; As[sk + 5][sr] = a1.y;
    As[sk + 6][sr] = a1.z; As[sk + 7][sr] = a1.w;
    Bs[sk + 0][sr] = b0.x; Bs[sk + 1][sr] = b0.y;
    Bs[sk + 2][sr] = b0.z; Bs[sk + 3][sr] = b0.w;
    Bs[sk + 4][sr] = b1.x; Bs[sk + 5][sr] = b1.y;
    Bs[sk + 6][sr] = b1.z; Bs[sk + 7][sr] = b1.w;
    __syncthreads();
#pragma unroll
    for (int kk = 0; kk < 32; ++kk) {
      float a[4], b[4];
      *(float4*)a = *(const float4*)&As[kk][ty * 4];
      *(float4*)b = *(const float4*)&Bs[kk][tx * 4];
#pragma unroll
      for (int i = 0; i < 4; ++i)
#pragma unroll
        for (int j = 0; j < 4; ++j) acc[i][j] += a[i] * b[j];
    }
    __syncthreads();
  }
  float bcol[4] = {0.f, 0.f, 0.f, 0.f};
  if (bias) *(float4*)bcol = *(const float4*)(bias + bn + tx * 4);
#pragma unroll
  for (int i = 0; i < 4; ++i) {
    int row = bm + ty * 4 + i;
    float4 o;
    o.x = acc[i][0] + bcol[0];
    o.y = acc[i][1] + bcol[1];
    o.z = acc[i][2] + bcol[2];
    o.w = acc[i][3] + bcol[3];
    *(float4*)(C + (size_t)row * ldc + bn + tx * 4) = o;
  }
}

// ---------------- fused e + softmax + context (one block per b, 512 threads)
__global__ __launch_bounds__(512) void step_attn(
    const float* __restrict__ fp, const float* __restrict__ hpg,  // [NB][2048]
    const float* __restrict__ w_score, const float* __restrict__ feats,
    float* __restrict__ context) {
  __shared__ float es[NT];
  __shared__ float als[NT];
  const int b = blockIdx.x;
  const int tid = threadIdx.x;
  const int lane = tid & 63, wid = tid >> 6;
  const float* hp = hpg + (size_t)b * 2048 + lane * 8;
  float4 h0 = *(const float4*)hp;
  float4 h1 = *(const float4*)(hp + 4);
  float4 w0 = *(const float4*)(w_score + lane * 8);
  float4 w1 = *(const float4*)(w_score + lane * 8 + 4);
#pragma unroll
  for (int i = 0; i < 8; ++i) {
    int t = wid * 8 + i;
    const float* fr = fp + ((size_t)t * NB + b) * HH + lane * 8;
    float4 f0 = *(const float4*)fr;
    float4 f1 = *(const float4*)(fr + 4);
    float acc = 0.f;
    acc += tanhf(f0.x + h0.x) * w0.x;
    acc += tanhf(f0.y + h0.y) * w0.y;
    acc += tanhf(f0.z + h0.z) * w0.z;
    acc += tanhf(f0.w + h0.w) * w0.w;
    acc += tanhf(f1.x + h1.x) * w1.x;
    acc += tanhf(f1.y + h1.y) * w1.y;
    acc += tanhf(f1.z + h1.z) * w1.z;
    acc += tanhf(f1.w + h1.w) * w1.w;
#pragma unroll
    for (int off = 32; off > 0; off >>= 1) acc += __shfl_down(acc, off, 64);
    if (lane == 0) es[t] = acc;
  }
  __syncthreads();
  if (tid < 64) {
    float v = es[tid];
    float mx = v;
#pragma unroll
    for (int off = 32; off > 0; off >>= 1) mx = fmaxf(mx, __shfl_xor(mx, off, 64));
    float p = expf(v - mx);
    float sum = p;
#pragma unroll
    for (int off = 32; off > 0; off >>= 1) sum += __shfl_xor(sum, off, 64);
    als[tid] = p / sum;
  }
  __syncthreads();
  float acc = 0.f;
  for (int t = 0; t < NT; ++t)
    acc += als[t] * feats[((size_t)t * NB + b) * NC + tid];
  context[(size_t)b * NC + tid] = acc;
}

// ---------------- fused GRU gates + logits + argmax (one block per b)
__global__ __launch_bounds__(128) void step_update(
    const float* __restrict__ hpg,  // [NB][2048], gh at cols 512..
    const float* __restrict__ gi0,  // [NB][1536]
    const float* __restrict__ P,    // [98][1536]
    const float* __restrict__ hc, float* __restrict__ hn_out,
    const float* __restrict__ w_gen, const float* __restrict__ b_gen,
    const int* __restrict__ tl, const int* __restrict__ offs,
    float* __restrict__ out, int* __restrict__ tgt, int step) {
  __shared__ float hs[HH];
  __shared__ float lv[128];
  __shared__ int li[128];
  const int b = blockIdx.x;
  const int tid = threadIdx.x;
  const int tg = tgt[b];
  const float* gib = gi0 + (size_t)b * 1536;
  const float* Pb = P + (size_t)tg * 1536;
  const float* ghb = hpg + (size_t)b * 2048 + 512;
#pragma unroll
  for (int i = 0; i < 4; ++i) {
    int j = tid + i * 128;
    float ir = gib[j] + Pb[j];
    float iz = gib[512 + j] + Pb[512 + j];
    float in = gib[1024 + j] + Pb[1024 + j];
    float hr = ghb[j], hz = ghb[512 + j], hn = ghb[1024 + j];
    float r = 1.f / (1.f + expf(-(ir + hr)));
    float z = 1.f / (1.f + expf(-(iz + hz)));
    float n = tanhf(in + r * hn);
    float h = hc[(size_t)b * HH + j];
    float hv = (1.f - z) * n + z * h;
    hs[j] = hv;
    hn_out[(size_t)b * HH + j] = hv;
  }
  __syncthreads();
  float acc = -INFINITY;
  if (tid < NCLS) {
    const float4* wr4 = (const float4*)(w_gen + (size_t)tid * HH);
    float s = 0.f;
    for (int k = 0; k < HH / 4; ++k) {
      float4 w = wr4[k];
      s += hs[4 * k + 0] * w.x + hs[4 * k + 1] * w.y +
           hs[4 * k + 2] * w.z + hs[4 * k + 3] * w.w;
    }
    acc = s + b_gen[tid];
    if (step < tl[b]) out[(size_t)(offs[b] + step) * NCLS + tid] = acc;
  }
  lv[tid] = acc;
  li[tid] = tid;
  __syncthreads();
  for (int d = 64; d > 0; d >>= 1) {
    if (tid < d) {
      float v2 = lv[tid + d];
      int i2 = li[tid + d];
      if (v2 > lv[tid] || (v2 == lv[tid] && i2 < li[tid])) {
        lv[tid] = v2;
        li[tid] = i2;
      }
    }
    __syncthreads();
  }
  if (tid == 0) tgt[b] = li[0] + 1;
}

// ---------------- one-time setup kernels
__global__ __launch_bounds__(256) void build_P(
    const float* __restrict__ char_emb, const float* __restrict__ w_ih,
    const float* __restrict__ b_ih, float* __restrict__ P) {
  __shared__ float emb[EE];
  int c = blockIdx.x;
  int tid = threadIdx.x;
  if (tid < EE) emb[tid] = char_emb[c * EE + tid];
  __syncthreads();
  for (int j = tid; j < 3 * HH; j += 256) {
    const float* wr = w_ih + (size_t)j * (NC + EE) + NC;
    float s = 0.f;
    for (int k = 0; k < EE; ++k) s += emb[k] * wr[k];
    P[(size_t)c * 1536 + j] = s + b_ih[j];
  }
}

__global__ __launch_bounds__(256) void build_wcat(
    const float* __restrict__ w_h2h, const float* __restrict__ w_hh,
    const float* __restrict__ b_h2h, const float* __restrict__ b_hh,
    float* __restrict__ Wcat, float* __restrict__ bcat) {
  int idx = blockIdx.x * 256 + threadIdx.x;  // float4 index, total 2048*512/4
  const int n1 = 512 * 512 / 4;
  float4* dst = (float4*)Wcat;
  if (idx < n1)
    dst[idx] = ((const float4*)w_h2h)[idx];
  else
    dst[idx] = ((const float4*)w_hh)[idx - n1];
  if (idx < 2048) bcat[idx] = (idx < 512) ? b_h2h[idx] : b_hh[idx - 512];
}

__global__ __launch_bounds__(1024) void scan_tl(const int* __restrict__ tl,
                                                int* __restrict__ offs) {
  __shared__ int s[NB];
  int t = threadIdx.x;
  s[t] = tl[t];
  __syncthreads();
  for (int d = 1; d < NB; d <<= 1) {
    int v = (t >= d) ? s[t - d] : 0;
    __syncthreads();
    s[t] += v;
    __syncthreads();
  }
  offs[t] = s[t] - tl[t];
}

__global__ __launch_bounds__(256) void init_kernel(float* __restrict__ h0,
                                                   int* __restrict__ tgt) {
  int idx = blockIdx.x * 256 + threadIdx.x;
  if (idx < NB * HH) h0[idx] = 0.f;
  if (idx < NB) tgt[idx] = 0;
}

extern "C" void kernel_launch(void* const* d_in, const int* in_sizes, int n_in,
                              void* d_out, int out_size, void* d_ws,
                              size_t ws_size, hipStream_t stream) {
  const float* feats = (const float*)d_in[0];
  const float* w_i2h = (const float*)d_in[1];
  const float* w_h2h = (const float*)d_in[2];
  const float* b_h2h = (const float*)d_in[3];
  const float* w_score = (const float*)d_in[4];
  const float* w_ih = (const float*)d_in[5];
  const float* w_hh = (const float*)d_in[6];
  const float* b_ih = (const float*)d_in[7];
  const float* b_hh = (const float*)d_in[8];
  const float* char_emb = (const float*)d_in[9];
  const float* w_gen = (const float*)d_in[10];
  const float* b_gen = (const float*)d_in[11];
  const int* tl = (const int*)d_in[12];
  float* out = (float*)d_out;

  char* ws = (char*)d_ws;
  float* fp = (float*)ws;      ws += (size_t)NT * NB * HH * 4;    // 134 MB
  float* C1 = (float*)ws;      ws += (size_t)NB * 2048 * 4;       // 8 MB
  float* gi0 = (float*)ws;     ws += (size_t)NB * 1536 * 4;       // 6 MB
  float* context = (float*)ws; ws += (size_t)NB * NC * 4;         // 2 MB
  float* h0 = (float*)ws;      ws += (size_t)NB * HH * 4;
  float* h1 = (float*)ws;      ws += (size_t)NB * HH * 4;
  float* Wcat = (float*)ws;    ws += (size_t)2048 * 512 * 4;      // 4 MB
  float* bcat = (float*)ws;    ws += 2048 * 4;
  float* P = (float*)ws;       ws += (size_t)98 * 1536 * 4;
  int* tgt = (int*)ws;         ws += 4096;
  int* offs = (int*)ws;        ws += 4096;

  hipLaunchKernelGGL(scan_tl, dim3(1), dim3(1024), 0, stream, tl, offs);
  hipLaunchKernelGGL(init_kernel, dim3((NB * HH) / 256), dim3(256), 0, stream,
                     h0, tgt);
  hipLaunchKernelGGL(build_wcat, dim3(1024), dim3(256), 0, stream, w_h2h, w_hh,
                     b_h2h, b_hh, Wcat, bcat);
  hipLaunchKernelGGL(build_P, dim3(98), dim3(256), 0, stream, char_emb, w_ih,
                     b_ih, P);
  // fp = feats @ w_i2h^T  [65536, 512]
  hipLaunchKernelGGL(gemm_bt_128, dim3(HH / 128, (NT * NB) / 128), dim3(256),
                     0, stream, feats, w_i2h, fp, NT * NB, HH, NC);

  float* hbuf[2] = {h0, h1};
  for (int s = 0; s < STEPS; ++s) {
    float* hc = hbuf[s & 1];
    float* hn = hbuf[(s + 1) & 1];
    // C1 = hc @ [w_h2h; w_hh]^T + [b_h2h; b_hh]   [1024, 2048]
    hipLaunchKernelGGL(gemm_bt_64, dim3(2048 / 64, NB / 64), dim3(256), 0,
                       stream, hc, HH, Wcat, 512, bcat, C1, 2048, HH);
    hipLaunchKernelGGL(step_attn, dim3(NB), dim3(512), 0, stream, fp, C1,
                       w_score, feats, context);
    // gi0 = context @ w_ih[:, :512]^T   [1024, 1536]
    hipLaunchKernelGGL(gemm_bt_64, dim3(1536 / 64, NB / 64), dim3(256), 0,
                       stream, context, NC, w_ih, NC + EE, (const float*)nullptr,
                       gi0, 1536, NC);
    hipLaunchKernelGGL(step_update, dim3(NB), dim3(128), 0, stream, C1, gi0, P,
                       hc, hn, w_gen, b_gen, tl, offs, out, tgt, s);
  }
}